// Round 1
// baseline (3672.132 us; speedup 1.0000x reference)
//
#include <hip/hip_runtime.h>

// GIN 3-layer forward on MI355X.
// x: 50000x128 f32, edge_index: 2x600000 int32, weights f32.
// Layer l: h = BN(relu(relu((x+agg)@Wa+ba)@Wb+bb))

constexpr int Nn = 50000;
constexpr int Ne = 600000;

// ---------------- copy x -> h (h then accumulates agg via atomics) --------
__global__ __launch_bounds__(256) void copy_f4(const float4* __restrict__ in,
                                               float4* __restrict__ out, int n4) {
  int i = blockIdx.x * 256 + threadIdx.x;
  if (i < n4) out[i] = in[i];
}

// ---------------- edge scatter-add: H[dst] += X[src] ----------------------
__global__ __launch_bounds__(256) void scatter_add(const float* __restrict__ X,
                                                   const int* __restrict__ src,
                                                   const int* __restrict__ dst,
                                                   float* __restrict__ H) {
  int idx = blockIdx.x * 256 + threadIdx.x;  // Ne*32 threads, 32 per edge (float4 each)
  if (idx >= Ne * 32) return;
  int e = idx >> 5, q = idx & 31;
  int s = src[e], d = dst[e];
  float4 v = ((const float4*)X)[s * 32 + q];
  float* o = H + (size_t)d * 128 + (q << 2);
  atomicAdd(o + 0, v.x);
  atomicAdd(o + 1, v.y);
  atomicAdd(o + 2, v.z);
  atomicAdd(o + 3, v.w);
}

// ---------------- C = relu(A @ W + b), A: nRows x 128, W: 128x128 ---------
// 64-row tile per block; W fully staged in LDS (64KB) + A tile (32KB).
// 256 threads; each computes 4 rows x 8 cols.
template <bool RELU>
__global__ __launch_bounds__(256) void gemm128(const float* __restrict__ A,
                                               const float* __restrict__ W,
                                               const float* __restrict__ bias,
                                               float* __restrict__ C, int nRows) {
  __shared__ float Ws[128 * 128];
  __shared__ float As[64][128];
  for (int i = threadIdx.x; i < 128 * 32; i += 256)
    ((float4*)Ws)[i] = ((const float4*)W)[i];
  int row0 = blockIdx.x * 64;
  for (int i = threadIdx.x; i < 64 * 32; i += 256) {
    int r = i >> 5, kc = i & 31;
    int row = row0 + r;
    float4 v = make_float4(0.f, 0.f, 0.f, 0.f);
    if (row < nRows) v = ((const float4*)A)[row * 32 + kc];
    ((float4*)&As[r][0])[kc] = v;
  }
  __syncthreads();
  int tx = threadIdx.x & 15, ty = threadIdx.x >> 4;
  int c0 = tx * 8;
  int rbase = ty * 4;
  float b8[8];
  *(float4*)&b8[0] = *(const float4*)&bias[c0];
  *(float4*)&b8[4] = *(const float4*)&bias[c0 + 4];
  float acc[4][8];
#pragma unroll
  for (int i = 0; i < 4; i++)
#pragma unroll
    for (int j = 0; j < 8; j++) acc[i][j] = b8[j];
#pragma unroll 8
  for (int k = 0; k < 128; k++) {
    float a[4];
#pragma unroll
    for (int i = 0; i < 4; i++) a[i] = As[rbase + i][k];
    float w[8];
    *(float4*)&w[0] = *(const float4*)&Ws[k * 128 + c0];
    *(float4*)&w[4] = *(const float4*)&Ws[k * 128 + c0 + 4];
#pragma unroll
    for (int i = 0; i < 4; i++)
#pragma unroll
      for (int j = 0; j < 8; j++) acc[i][j] = fmaf(a[i], w[j], acc[i][j]);
  }
#pragma unroll
  for (int i = 0; i < 4; i++) {
    int row = row0 + rbase + i;
    if (row >= nRows) continue;
    float o[8];
#pragma unroll
    for (int j = 0; j < 8; j++) o[j] = RELU ? fmaxf(acc[i][j], 0.f) : acc[i][j];
    *(float4*)&C[(size_t)row * 128 + c0] = *(float4*)&o[0];
    *(float4*)&C[(size_t)row * 128 + c0 + 4] = *(float4*)&o[4];
  }
}

// ---------------- O = relu(A @ W + b), W: 128x2 (final layer) -------------
__global__ __launch_bounds__(256) void gemm_out2(const float* __restrict__ A,
                                                 const float* __restrict__ W,
                                                 const float* __restrict__ bias,
                                                 float* __restrict__ O, int nRows) {
  __shared__ float Wc[256];
  Wc[threadIdx.x] = W[threadIdx.x];
  __syncthreads();
  int row = blockIdx.x * 256 + threadIdx.x;
  if (row >= nRows) return;
  float a0 = bias[0], a1 = bias[1];
  const float4* a4 = (const float4*)(A + (size_t)row * 128);
#pragma unroll
  for (int q = 0; q < 32; q++) {
    float4 v = a4[q];
    a0 = fmaf(v.x, Wc[(q * 4 + 0) * 2 + 0], a0);
    a1 = fmaf(v.x, Wc[(q * 4 + 0) * 2 + 1], a1);
    a0 = fmaf(v.y, Wc[(q * 4 + 1) * 2 + 0], a0);
    a1 = fmaf(v.y, Wc[(q * 4 + 1) * 2 + 1], a1);
    a0 = fmaf(v.z, Wc[(q * 4 + 2) * 2 + 0], a0);
    a1 = fmaf(v.z, Wc[(q * 4 + 2) * 2 + 1], a1);
    a0 = fmaf(v.w, Wc[(q * 4 + 3) * 2 + 0], a0);
    a1 = fmaf(v.w, Wc[(q * 4 + 3) * 2 + 1], a1);
  }
  O[row * 2 + 0] = fmaxf(a0, 0.f);
  O[row * 2 + 1] = fmaxf(a1, 0.f);
}

// ---------------- BN stats: per-feature sum and sumsq ---------------------
template <int C>
__global__ __launch_bounds__(256) void bn_stats(const float* __restrict__ H,
                                                float* __restrict__ sums, int nRows) {
  int idx = blockIdx.x * 256 + threadIdx.x;
  int total = gridDim.x * 256;
  int f = idx % C;
  int rstride = total / C;  // launch so total % C == 0
  float s = 0.f, sq = 0.f;
  for (int r = idx / C; r < nRows; r += rstride) {
    float v = H[(size_t)r * C + f];
    s += v;
    sq += v * v;
  }
  atomicAdd(&sums[f], s);
  atomicAdd(&sums[C + f], sq);
}

// ---------------- BN apply ------------------------------------------------
template <int C>
__global__ __launch_bounds__(256) void bn_apply(const float* __restrict__ H,
                                                const float* __restrict__ sums,
                                                const float* __restrict__ gamma,
                                                const float* __restrict__ beta,
                                                float* __restrict__ Out, int nRows) {
  int idx = blockIdx.x * 256 + threadIdx.x;
  if (idx >= nRows * C) return;
  int f = idx % C;
  float mean = sums[f] * (1.0f / Nn);
  float var = sums[C + f] * (1.0f / Nn) - mean * mean;
  float inv = rsqrtf(var + 1e-5f);
  Out[idx] = (H[idx] - mean) * inv * gamma[f] + beta[f];
}

extern "C" void kernel_launch(void* const* d_in, const int* in_sizes, int n_in,
                              void* d_out, int out_size, void* d_ws, size_t ws_size,
                              hipStream_t stream) {
  const float* x = (const float*)d_in[0];
  const int* src = (const int*)d_in[1];
  const int* dst = src + Ne;
  const float* W1a = (const float*)d_in[2];
  const float* b1a = (const float*)d_in[3];
  const float* W1b = (const float*)d_in[4];
  const float* b1b = (const float*)d_in[5];
  const float* g1 = (const float*)d_in[6];
  const float* be1 = (const float*)d_in[7];
  const float* W2a = (const float*)d_in[8];
  const float* b2a = (const float*)d_in[9];
  const float* W2b = (const float*)d_in[10];
  const float* b2b = (const float*)d_in[11];
  const float* g2 = (const float*)d_in[12];
  const float* be2 = (const float*)d_in[13];
  const float* W5a = (const float*)d_in[14];
  const float* b5a = (const float*)d_in[15];
  const float* W5b = (const float*)d_in[16];
  const float* b5b = (const float*)d_in[17];
  const float* g5 = (const float*)d_in[18];
  const float* be5 = (const float*)d_in[19];

  float* ws = (float*)d_ws;
  float* hbuf = ws;                     // Nn*128
  float* tbuf = ws + (size_t)Nn * 128;  // Nn*128
  float* cbuf = ws + (size_t)2 * Nn * 128;
  float* stats = ws + (size_t)3 * Nn * 128;  // 256 + 256 + 4 floats
  float* st1 = stats, *st2 = stats + 256, *st3 = stats + 512;

  // fresh stats every launch (d_ws is NOT re-poisoned between replays)
  hipMemsetAsync(stats, 0, (512 + 4) * sizeof(float), stream);

  const int copyGrid = (Nn * 32 + 255) / 256;
  const int scatGrid = (Ne * 32 + 255) / 256;
  const int gemmGrid = (Nn + 63) / 64;

  // ---- layer 1: x -> cbuf ----
  copy_f4<<<copyGrid, 256, 0, stream>>>((const float4*)x, (float4*)hbuf, Nn * 32);
  scatter_add<<<scatGrid, 256, 0, stream>>>(x, src, dst, hbuf);
  gemm128<true><<<gemmGrid, 256, 0, stream>>>(hbuf, W1a, b1a, tbuf, Nn);
  gemm128<true><<<gemmGrid, 256, 0, stream>>>(tbuf, W1b, b1b, hbuf, Nn);
  bn_stats<128><<<128, 256, 0, stream>>>(hbuf, st1, Nn);
  bn_apply<128><<<(Nn * 128 + 255) / 256, 256, 0, stream>>>(hbuf, st1, g1, be1, cbuf, Nn);

  // ---- layer 2: cbuf -> cbuf ----
  copy_f4<<<copyGrid, 256, 0, stream>>>((const float4*)cbuf, (float4*)hbuf, Nn * 32);
  scatter_add<<<scatGrid, 256, 0, stream>>>(cbuf, src, dst, hbuf);
  gemm128<true><<<gemmGrid, 256, 0, stream>>>(hbuf, W2a, b2a, tbuf, Nn);
  gemm128<true><<<gemmGrid, 256, 0, stream>>>(tbuf, W2b, b2b, hbuf, Nn);
  bn_stats<128><<<128, 256, 0, stream>>>(hbuf, st2, Nn);
  bn_apply<128><<<(Nn * 128 + 255) / 256, 256, 0, stream>>>(hbuf, st2, g2, be2, cbuf, Nn);

  // ---- layer 3: cbuf -> d_out (feature dim 2) ----
  copy_f4<<<copyGrid, 256, 0, stream>>>((const float4*)cbuf, (float4*)hbuf, Nn * 32);
  scatter_add<<<scatGrid, 256, 0, stream>>>(cbuf, src, dst, hbuf);
  gemm128<true><<<gemmGrid, 256, 0, stream>>>(hbuf, W5a, b5a, tbuf, Nn);
  gemm_out2<<<(Nn + 255) / 256, 256, 0, stream>>>(tbuf, W5b, b5b, hbuf, Nn);
  bn_stats<2><<<64, 256, 0, stream>>>(hbuf, st3, Nn);
  bn_apply<2><<<(Nn * 2 + 255) / 256, 256, 0, stream>>>(hbuf, st3, g5, be5, (float*)d_out, Nn);
}

// Round 2
// 937.150 us; speedup vs baseline: 3.9184x; 3.9184x over previous
//
#include <hip/hip_runtime.h>

// GIN 3-layer forward on MI355X — round 2: CSR-gather aggregation (no f32 atomics),
// BN-apply folded into the next layer's gather.

constexpr int Nn = 50000;
constexpr int Ne = 600000;

// ---------------- CSR build ----------------------------------------------
__global__ __launch_bounds__(256) void edge_hist(const int* __restrict__ dst,
                                                 int* __restrict__ rp) {
  int e = blockIdx.x * 256 + threadIdx.x;
  if (e < Ne) atomicAdd(&rp[dst[e] + 1], 1);
}

// single-block inclusive scan of rp[0..Nn]
__global__ __launch_bounds__(1024) void scan_rowptr(int* __restrict__ rp) {
  __shared__ int buf[1024];
  __shared__ int carry;
  if (threadIdx.x == 0) carry = 0;
  __syncthreads();
  for (int base = 0; base < Nn + 1; base += 1024) {
    int i = base + threadIdx.x;
    int v = (i < Nn + 1) ? rp[i] : 0;
    buf[threadIdx.x] = v;
    __syncthreads();
#pragma unroll
    for (int off = 1; off < 1024; off <<= 1) {
      int t = (threadIdx.x >= off) ? buf[threadIdx.x - off] : 0;
      __syncthreads();
      buf[threadIdx.x] += t;
      __syncthreads();
    }
    int inc = buf[threadIdx.x] + carry;
    if (i < Nn + 1) rp[i] = inc;
    __syncthreads();
    if (threadIdx.x == 1023) carry = inc;
    __syncthreads();
  }
}

__global__ __launch_bounds__(256) void copy_cur(const int* __restrict__ rp,
                                                int* __restrict__ cur) {
  int i = blockIdx.x * 256 + threadIdx.x;
  if (i < Nn) cur[i] = rp[i];
}

__global__ __launch_bounds__(256) void edge_fill(const int* __restrict__ src,
                                                 const int* __restrict__ dst,
                                                 int* __restrict__ cur,
                                                 int* __restrict__ cols) {
  int e = blockIdx.x * 256 + threadIdx.x;
  if (e < Ne) {
    int p = atomicAdd(&cur[dst[e]], 1);
    cols[p] = src[e];
  }
}

// ---------------- gather: H[i] = sum over {i} u neighbors of affine(X[row]) ----
// One wave (64 lanes) per node; float2 per lane covers 128 features.
// FOLD: apply previous layer's BN as per-element affine v*A_f + B_f on the fly:
//   sum over cnt elements = A_f * sum(v) + cnt * B_f.
template <bool FOLD>
__global__ __launch_bounds__(256) void gather_bn(const float* __restrict__ X,
                                                 const int* __restrict__ rp,
                                                 const int* __restrict__ cols,
                                                 const float* __restrict__ sums,
                                                 const float* __restrict__ gamma,
                                                 const float* __restrict__ beta,
                                                 float* __restrict__ H) {
  int wid = (blockIdx.x * 256 + threadIdx.x) >> 6;
  if (wid >= Nn) return;
  int lane = threadIdx.x & 63;
  int f0 = lane * 2;
  float A0 = 1.f, A1 = 1.f, B0 = 0.f, B1 = 0.f;
  if (FOLD) {
    float m0 = sums[f0] * (1.f / Nn), m1 = sums[f0 + 1] * (1.f / Nn);
    float v0 = sums[128 + f0] * (1.f / Nn) - m0 * m0;
    float v1 = sums[128 + f0 + 1] * (1.f / Nn) - m1 * m1;
    A0 = rsqrtf(v0 + 1e-5f) * gamma[f0];
    A1 = rsqrtf(v1 + 1e-5f) * gamma[f0 + 1];
    B0 = beta[f0] - m0 * A0;
    B1 = beta[f0 + 1] - m1 * A1;
  }
  int p0 = rp[wid], p1 = rp[wid + 1];
  float2 acc = *(const float2*)&X[(size_t)wid * 128 + f0];
  for (int p = p0; p < p1; ++p) {
    int s = cols[p];
    float2 v = *(const float2*)&X[(size_t)s * 128 + f0];
    acc.x += v.x;
    acc.y += v.y;
  }
  float cnt = (float)(p1 - p0 + 1);
  float2 o;
  o.x = FOLD ? A0 * acc.x + cnt * B0 : acc.x;
  o.y = FOLD ? A1 * acc.y + cnt * B1 : acc.y;
  *(float2*)&H[(size_t)wid * 128 + f0] = o;
}

// ---------------- C = relu(A @ W + b), A: nRows x 128, W: 128x128 ---------
template <bool RELU>
__global__ __launch_bounds__(256) void gemm128(const float* __restrict__ A,
                                               const float* __restrict__ W,
                                               const float* __restrict__ bias,
                                               float* __restrict__ C, int nRows) {
  __shared__ float Ws[128 * 128];
  __shared__ float As[64][128];
  for (int i = threadIdx.x; i < 128 * 32; i += 256)
    ((float4*)Ws)[i] = ((const float4*)W)[i];
  int row0 = blockIdx.x * 64;
  for (int i = threadIdx.x; i < 64 * 32; i += 256) {
    int r = i >> 5, kc = i & 31;
    int row = row0 + r;
    float4 v = make_float4(0.f, 0.f, 0.f, 0.f);
    if (row < nRows) v = ((const float4*)A)[row * 32 + kc];
    ((float4*)&As[r][0])[kc] = v;
  }
  __syncthreads();
  int tx = threadIdx.x & 15, ty = threadIdx.x >> 4;
  int c0 = tx * 8;
  int rbase = ty * 4;
  float b8[8];
  *(float4*)&b8[0] = *(const float4*)&bias[c0];
  *(float4*)&b8[4] = *(const float4*)&bias[c0 + 4];
  float acc[4][8];
#pragma unroll
  for (int i = 0; i < 4; i++)
#pragma unroll
    for (int j = 0; j < 8; j++) acc[i][j] = b8[j];
#pragma unroll 8
  for (int k = 0; k < 128; k++) {
    float a[4];
#pragma unroll
    for (int i = 0; i < 4; i++) a[i] = As[rbase + i][k];
    float w[8];
    *(float4*)&w[0] = *(const float4*)&Ws[k * 128 + c0];
    *(float4*)&w[4] = *(const float4*)&Ws[k * 128 + c0 + 4];
#pragma unroll
    for (int i = 0; i < 4; i++)
#pragma unroll
      for (int j = 0; j < 8; j++) acc[i][j] = fmaf(a[i], w[j], acc[i][j]);
  }
#pragma unroll
  for (int i = 0; i < 4; i++) {
    int row = row0 + rbase + i;
    if (row >= nRows) continue;
    float o[8];
#pragma unroll
    for (int j = 0; j < 8; j++) o[j] = RELU ? fmaxf(acc[i][j], 0.f) : acc[i][j];
    *(float4*)&C[(size_t)row * 128 + c0] = *(float4*)&o[0];
    *(float4*)&C[(size_t)row * 128 + c0 + 4] = *(float4*)&o[4];
  }
}

// ---------------- O = relu(A @ W + b), W: 128x2 (final layer) -------------
__global__ __launch_bounds__(256) void gemm_out2(const float* __restrict__ A,
                                                 const float* __restrict__ W,
                                                 const float* __restrict__ bias,
                                                 float* __restrict__ O, int nRows) {
  __shared__ float Wc[256];
  Wc[threadIdx.x] = W[threadIdx.x];
  __syncthreads();
  int row = blockIdx.x * 256 + threadIdx.x;
  if (row >= nRows) return;
  float a0 = bias[0], a1 = bias[1];
  const float4* a4 = (const float4*)(A + (size_t)row * 128);
#pragma unroll
  for (int q = 0; q < 32; q++) {
    float4 v = a4[q];
    a0 = fmaf(v.x, Wc[(q * 4 + 0) * 2 + 0], a0);
    a1 = fmaf(v.x, Wc[(q * 4 + 0) * 2 + 1], a1);
    a0 = fmaf(v.y, Wc[(q * 4 + 1) * 2 + 0], a0);
    a1 = fmaf(v.y, Wc[(q * 4 + 1) * 2 + 1], a1);
    a0 = fmaf(v.z, Wc[(q * 4 + 2) * 2 + 0], a0);
    a1 = fmaf(v.z, Wc[(q * 4 + 2) * 2 + 1], a1);
    a0 = fmaf(v.w, Wc[(q * 4 + 3) * 2 + 0], a0);
    a1 = fmaf(v.w, Wc[(q * 4 + 3) * 2 + 1], a1);
  }
  O[row * 2 + 0] = fmaxf(a0, 0.f);
  O[row * 2 + 1] = fmaxf(a1, 0.f);
}

// ---------------- BN stats: per-feature sum and sumsq ---------------------
template <int C>
__global__ __launch_bounds__(256) void bn_stats(const float* __restrict__ H,
                                                float* __restrict__ sums, int nRows) {
  int idx = blockIdx.x * 256 + threadIdx.x;
  int total = gridDim.x * 256;
  int f = idx % C;
  int rstride = total / C;
  float s = 0.f, sq = 0.f;
  for (int r = idx / C; r < nRows; r += rstride) {
    float v = H[(size_t)r * C + f];
    s += v;
    sq += v * v;
  }
  atomicAdd(&sums[f], s);
  atomicAdd(&sums[C + f], sq);
}

// ---------------- BN apply (final 2-feature layer only) -------------------
template <int C>
__global__ __launch_bounds__(256) void bn_apply(const float* __restrict__ H,
                                                const float* __restrict__ sums,
                                                const float* __restrict__ gamma,
                                                const float* __restrict__ beta,
                                                float* __restrict__ Out, int nRows) {
  int idx = blockIdx.x * 256 + threadIdx.x;
  if (idx >= nRows * C) return;
  int f = idx % C;
  float mean = sums[f] * (1.0f / Nn);
  float var = sums[C + f] * (1.0f / Nn) - mean * mean;
  float inv = rsqrtf(var + 1e-5f);
  Out[idx] = (H[idx] - mean) * inv * gamma[f] + beta[f];
}

extern "C" void kernel_launch(void* const* d_in, const int* in_sizes, int n_in,
                              void* d_out, int out_size, void* d_ws, size_t ws_size,
                              hipStream_t stream) {
  const float* x = (const float*)d_in[0];
  const int* src = (const int*)d_in[1];
  const int* dst = src + Ne;
  const float* W1a = (const float*)d_in[2];
  const float* b1a = (const float*)d_in[3];
  const float* W1b = (const float*)d_in[4];
  const float* b1b = (const float*)d_in[5];
  const float* g1 = (const float*)d_in[6];
  const float* be1 = (const float*)d_in[7];
  const float* W2a = (const float*)d_in[8];
  const float* b2a = (const float*)d_in[9];
  const float* W2b = (const float*)d_in[10];
  const float* b2b = (const float*)d_in[11];
  const float* g2 = (const float*)d_in[12];
  const float* be2 = (const float*)d_in[13];
  const float* W5a = (const float*)d_in[14];
  const float* b5a = (const float*)d_in[15];
  const float* W5b = (const float*)d_in[16];
  const float* b5b = (const float*)d_in[17];
  const float* g5 = (const float*)d_in[18];
  const float* be5 = (const float*)d_in[19];

  float* ws = (float*)d_ws;
  float* bufA = ws;                          // Nn*128
  float* bufB = ws + (size_t)Nn * 128;       // Nn*128
  float* stats = ws + (size_t)2 * Nn * 128;  // 516 floats used
  float* st1 = stats, *st2 = stats + 256, *st3 = stats + 512;
  int* rowptr = (int*)(stats + 520);  // Nn+1
  int* cur = rowptr + Nn + 1;         // Nn
  int* cols = cur + Nn;               // Ne
  float* o2buf = bufA;                // Nn*2, reused after bufA is consumed

  // fresh state every launch (harness does not re-poison ws between replays)
  hipMemsetAsync(stats, 0, 520 * sizeof(float), stream);
  hipMemsetAsync(rowptr, 0, (Nn + 1) * sizeof(int), stream);

  const int eGrid = (Ne + 255) / 256;
  const int nGrid = (Nn + 255) / 256;
  const int gatherGrid = (Nn * 64 + 255) / 256;
  const int gemmGrid = (Nn + 63) / 64;

  // ---- CSR build (once; reused by all 3 layers) ----
  edge_hist<<<eGrid, 256, 0, stream>>>(dst, rowptr);
  scan_rowptr<<<1, 1024, 0, stream>>>(rowptr);
  copy_cur<<<nGrid, 256, 0, stream>>>(rowptr, cur);
  edge_fill<<<eGrid, 256, 0, stream>>>(src, dst, cur, cols);

  // ---- layer 1 ----
  gather_bn<false><<<gatherGrid, 256, 0, stream>>>(x, rowptr, cols, nullptr, nullptr,
                                                   nullptr, bufA);
  gemm128<true><<<gemmGrid, 256, 0, stream>>>(bufA, W1a, b1a, bufB, Nn);
  gemm128<true><<<gemmGrid, 256, 0, stream>>>(bufB, W1b, b1b, bufA, Nn);  // bufA = h1 raw
  bn_stats<128><<<128, 256, 0, stream>>>(bufA, st1, Nn);

  // ---- layer 2 (BN1 folded into gather) ----
  gather_bn<true><<<gatherGrid, 256, 0, stream>>>(bufA, rowptr, cols, st1, g1, be1, bufB);
  gemm128<true><<<gemmGrid, 256, 0, stream>>>(bufB, W2a, b2a, bufA, Nn);
  gemm128<true><<<gemmGrid, 256, 0, stream>>>(bufA, W2b, b2b, bufB, Nn);  // bufB = h2 raw
  bn_stats<128><<<128, 256, 0, stream>>>(bufB, st2, Nn);

  // ---- layer 3 (BN2 folded into gather; output dim 2) ----
  gather_bn<true><<<gatherGrid, 256, 0, stream>>>(bufB, rowptr, cols, st2, g2, be2, bufA);
  gemm128<true><<<gemmGrid, 256, 0, stream>>>(bufA, W5a, b5a, bufB, Nn);
  gemm_out2<<<nGrid, 256, 0, stream>>>(bufB, W5b, b5b, o2buf, Nn);
  bn_stats<2><<<64, 256, 0, stream>>>(o2buf, st3, Nn);
  bn_apply<2><<<(Nn * 2 + 255) / 256, 256, 0, stream>>>(o2buf, st3, g5, be5,
                                                        (float*)d_out, Nn);
}

// Round 3
// 635.793 us; speedup vs baseline: 5.7757x; 1.4740x over previous
//
#include <hip/hip_runtime.h>

// GIN 3-layer forward on MI355X — round 3: BN-stats fused into GEMM epilogues.

constexpr int Nn = 50000;
constexpr int Ne = 600000;

// ---------------- CSR build ----------------------------------------------
__global__ __launch_bounds__(256) void edge_hist(const int* __restrict__ dst,
                                                 int* __restrict__ rp) {
  int e = blockIdx.x * 256 + threadIdx.x;
  if (e < Ne) atomicAdd(&rp[dst[e] + 1], 1);
}

// single-block scan of rp[0..Nn] via wave shfl-scan (2 syncs per 1024 chunk)
__global__ __launch_bounds__(1024) void scan_rowptr(int* __restrict__ rp) {
  __shared__ int wsum[16];
  __shared__ int wpre[16];
  __shared__ int carry;
  if (threadIdx.x == 0) carry = 0;
  __syncthreads();
  int lane = threadIdx.x & 63;
  int wv = threadIdx.x >> 6;
  for (int base = 0; base < Nn + 1; base += 1024) {
    int i = base + threadIdx.x;
    int v = (i < Nn + 1) ? rp[i] : 0;
#pragma unroll
    for (int off = 1; off < 64; off <<= 1) {
      int t = __shfl_up(v, off);
      if (lane >= off) v += t;
    }
    if (lane == 63) wsum[wv] = v;
    __syncthreads();
    if (threadIdx.x == 0) {
      int acc = carry;
#pragma unroll
      for (int w = 0; w < 16; w++) {
        wpre[w] = acc;
        acc += wsum[w];
      }
      carry = acc;
    }
    __syncthreads();
    if (i < Nn + 1) rp[i] = v + wpre[wv];
  }
}

__global__ __launch_bounds__(256) void copy_cur(const int* __restrict__ rp,
                                                int* __restrict__ cur) {
  int i = blockIdx.x * 256 + threadIdx.x;
  if (i < Nn) cur[i] = rp[i];
}

__global__ __launch_bounds__(256) void edge_fill(const int* __restrict__ src,
                                                 const int* __restrict__ dst,
                                                 int* __restrict__ cur,
                                                 int* __restrict__ cols) {
  int e = blockIdx.x * 256 + threadIdx.x;
  if (e < Ne) {
    int p = atomicAdd(&cur[dst[e]], 1);
    cols[p] = src[e];
  }
}

// ---------------- gather: H[i] = (1+deg-weighted) sum of affine(X[nbr]) ----
template <bool FOLD>
__global__ __launch_bounds__(256) void gather_bn(const float* __restrict__ X,
                                                 const int* __restrict__ rp,
                                                 const int* __restrict__ cols,
                                                 const float* __restrict__ sums,
                                                 const float* __restrict__ gamma,
                                                 const float* __restrict__ beta,
                                                 float* __restrict__ H) {
  int wid = (blockIdx.x * 256 + threadIdx.x) >> 6;
  if (wid >= Nn) return;
  int lane = threadIdx.x & 63;
  int f0 = lane * 2;
  float A0 = 1.f, A1 = 1.f, B0 = 0.f, B1 = 0.f;
  if (FOLD) {
    float m0 = sums[f0] * (1.f / Nn), m1 = sums[f0 + 1] * (1.f / Nn);
    float v0 = sums[128 + f0] * (1.f / Nn) - m0 * m0;
    float v1 = sums[128 + f0 + 1] * (1.f / Nn) - m1 * m1;
    A0 = rsqrtf(v0 + 1e-5f) * gamma[f0];
    A1 = rsqrtf(v1 + 1e-5f) * gamma[f0 + 1];
    B0 = beta[f0] - m0 * A0;
    B1 = beta[f0 + 1] - m1 * A1;
  }
  int p0 = rp[wid], p1 = rp[wid + 1];
  float2 acc = *(const float2*)&X[(size_t)wid * 128 + f0];
  for (int p = p0; p < p1; ++p) {
    int s = cols[p];
    float2 v = *(const float2*)&X[(size_t)s * 128 + f0];
    acc.x += v.x;
    acc.y += v.y;
  }
  float cnt = (float)(p1 - p0 + 1);
  float2 o;
  o.x = FOLD ? A0 * acc.x + cnt * B0 : acc.x;
  o.y = FOLD ? A1 * acc.y + cnt * B1 : acc.y;
  *(float2*)&H[(size_t)wid * 128 + f0] = o;
}

// ---------------- C = relu(A @ W + b); optional fused per-feature stats ----
template <bool STATS>
__global__ __launch_bounds__(256) void gemm128(const float* __restrict__ A,
                                               const float* __restrict__ W,
                                               const float* __restrict__ bias,
                                               float* __restrict__ C,
                                               float* __restrict__ stats, int nRows) {
  __shared__ float Ws[128 * 128];
  __shared__ float As[64][128];
  for (int i = threadIdx.x; i < 128 * 32; i += 256)
    ((float4*)Ws)[i] = ((const float4*)W)[i];
  int row0 = blockIdx.x * 64;
  for (int i = threadIdx.x; i < 64 * 32; i += 256) {
    int r = i >> 5, kc = i & 31;
    int row = row0 + r;
    float4 v = make_float4(0.f, 0.f, 0.f, 0.f);
    if (row < nRows) v = ((const float4*)A)[row * 32 + kc];
    ((float4*)&As[r][0])[kc] = v;
  }
  __syncthreads();
  int tx = threadIdx.x & 15, ty = threadIdx.x >> 4;
  int c0 = tx * 8;
  int rbase = ty * 4;
  float b8[8];
  *(float4*)&b8[0] = *(const float4*)&bias[c0];
  *(float4*)&b8[4] = *(const float4*)&bias[c0 + 4];
  float acc[4][8];
#pragma unroll
  for (int i = 0; i < 4; i++)
#pragma unroll
    for (int j = 0; j < 8; j++) acc[i][j] = b8[j];
#pragma unroll 8
  for (int k = 0; k < 128; k++) {
    float a[4];
#pragma unroll
    for (int i = 0; i < 4; i++) a[i] = As[rbase + i][k];
    float w[8];
    *(float4*)&w[0] = *(const float4*)&Ws[k * 128 + c0];
    *(float4*)&w[4] = *(const float4*)&Ws[k * 128 + c0 + 4];
#pragma unroll
    for (int i = 0; i < 4; i++)
#pragma unroll
      for (int j = 0; j < 8; j++) acc[i][j] = fmaf(a[i], w[j], acc[i][j]);
  }
  float s[8], sq[8];
#pragma unroll
  for (int j = 0; j < 8; j++) { s[j] = 0.f; sq[j] = 0.f; }
#pragma unroll
  for (int i = 0; i < 4; i++) {
    int row = row0 + rbase + i;
    if (row >= nRows) continue;
    float o[8];
#pragma unroll
    for (int j = 0; j < 8; j++) {
      o[j] = fmaxf(acc[i][j], 0.f);
      if (STATS) { s[j] += o[j]; sq[j] += o[j] * o[j]; }
    }
    *(float4*)&C[(size_t)row * 128 + c0] = *(float4*)&o[0];
    *(float4*)&C[(size_t)row * 128 + c0 + 4] = *(float4*)&o[4];
  }
  if (STATS) {
    __shared__ float redS[4][128];
    __shared__ float redQ[4][128];
#pragma unroll
    for (int j = 0; j < 8; j++) {
      s[j] += __shfl_xor(s[j], 16);
      s[j] += __shfl_xor(s[j], 32);
      sq[j] += __shfl_xor(sq[j], 16);
      sq[j] += __shfl_xor(sq[j], 32);
    }
    int wave = threadIdx.x >> 6;
    int lane = threadIdx.x & 63;
    if (lane < 16) {
#pragma unroll
      for (int j = 0; j < 8; j++) {
        redS[wave][lane * 8 + j] = s[j];
        redQ[wave][lane * 8 + j] = sq[j];
      }
    }
    __syncthreads();
    if (threadIdx.x < 128) {
      float ts = redS[0][threadIdx.x] + redS[1][threadIdx.x] + redS[2][threadIdx.x] +
                 redS[3][threadIdx.x];
      float tq = redQ[0][threadIdx.x] + redQ[1][threadIdx.x] + redQ[2][threadIdx.x] +
                 redQ[3][threadIdx.x];
      atomicAdd(&stats[threadIdx.x], ts);
      atomicAdd(&stats[128 + threadIdx.x], tq);
    }
  }
}

// ---------------- O = relu(A @ W + b), W: 128x2, fused stats --------------
__global__ __launch_bounds__(256) void gemm_out2(const float* __restrict__ A,
                                                 const float* __restrict__ W,
                                                 const float* __restrict__ bias,
                                                 float* __restrict__ O,
                                                 float* __restrict__ stats, int nRows) {
  __shared__ float Wc[256];
  Wc[threadIdx.x] = W[threadIdx.x];
  __syncthreads();
  int row = blockIdx.x * 256 + threadIdx.x;
  float o0 = 0.f, o1 = 0.f;
  if (row < nRows) {
    float a0 = bias[0], a1 = bias[1];
    const float4* a4 = (const float4*)(A + (size_t)row * 128);
#pragma unroll
    for (int q = 0; q < 32; q++) {
      float4 v = a4[q];
      a0 = fmaf(v.x, Wc[(q * 4 + 0) * 2 + 0], a0);
      a1 = fmaf(v.x, Wc[(q * 4 + 0) * 2 + 1], a1);
      a0 = fmaf(v.y, Wc[(q * 4 + 1) * 2 + 0], a0);
      a1 = fmaf(v.y, Wc[(q * 4 + 1) * 2 + 1], a1);
      a0 = fmaf(v.z, Wc[(q * 4 + 2) * 2 + 0], a0);
      a1 = fmaf(v.z, Wc[(q * 4 + 2) * 2 + 1], a1);
      a0 = fmaf(v.w, Wc[(q * 4 + 3) * 2 + 0], a0);
      a1 = fmaf(v.w, Wc[(q * 4 + 3) * 2 + 1], a1);
    }
    o0 = fmaxf(a0, 0.f);
    o1 = fmaxf(a1, 0.f);
    O[row * 2 + 0] = o0;
    O[row * 2 + 1] = o1;
  }
  float s0 = o0, q0 = o0 * o0, s1 = o1, q1 = o1 * o1;
#pragma unroll
  for (int off = 32; off; off >>= 1) {
    s0 += __shfl_down(s0, off);
    q0 += __shfl_down(q0, off);
    s1 += __shfl_down(s1, off);
    q1 += __shfl_down(q1, off);
  }
  if ((threadIdx.x & 63) == 0) {
    atomicAdd(&stats[0], s0);
    atomicAdd(&stats[1], s1);
    atomicAdd(&stats[2], q0);
    atomicAdd(&stats[3], q1);
  }
}

// ---------------- BN apply (final 2-feature layer only) -------------------
__global__ __launch_bounds__(256) void bn_apply2(const float* __restrict__ H,
                                                 const float* __restrict__ sums,
                                                 const float* __restrict__ gamma,
                                                 const float* __restrict__ beta,
                                                 float* __restrict__ Out, int nRows) {
  int idx = blockIdx.x * 256 + threadIdx.x;
  if (idx >= nRows * 2) return;
  int f = idx & 1;
  float mean = sums[f] * (1.0f / Nn);
  float var = sums[2 + f] * (1.0f / Nn) - mean * mean;
  float inv = rsqrtf(var + 1e-5f);
  Out[idx] = (H[idx] - mean) * inv * gamma[f] + beta[f];
}

extern "C" void kernel_launch(void* const* d_in, const int* in_sizes, int n_in,
                              void* d_out, int out_size, void* d_ws, size_t ws_size,
                              hipStream_t stream) {
  const float* x = (const float*)d_in[0];
  const int* src = (const int*)d_in[1];
  const int* dst = src + Ne;
  const float* W1a = (const float*)d_in[2];
  const float* b1a = (const float*)d_in[3];
  const float* W1b = (const float*)d_in[4];
  const float* b1b = (const float*)d_in[5];
  const float* g1 = (const float*)d_in[6];
  const float* be1 = (const float*)d_in[7];
  const float* W2a = (const float*)d_in[8];
  const float* b2a = (const float*)d_in[9];
  const float* W2b = (const float*)d_in[10];
  const float* b2b = (const float*)d_in[11];
  const float* g2 = (const float*)d_in[12];
  const float* be2 = (const float*)d_in[13];
  const float* W5a = (const float*)d_in[14];
  const float* b5a = (const float*)d_in[15];
  const float* W5b = (const float*)d_in[16];
  const float* b5b = (const float*)d_in[17];
  const float* g5 = (const float*)d_in[18];
  const float* be5 = (const float*)d_in[19];

  float* ws = (float*)d_ws;
  float* bufA = ws;                          // Nn*128
  float* bufB = ws + (size_t)Nn * 128;       // Nn*128
  float* stats = ws + (size_t)2 * Nn * 128;  // 520 floats used
  float* st1 = stats, *st2 = stats + 256, *st3 = stats + 512;
  int* rowptr = (int*)(stats + 520);  // Nn+1
  int* cur = rowptr + Nn + 1;         // Nn
  int* cols = cur + Nn;               // Ne
  float* o2buf = bufA;                // Nn*2, reused after bufA is consumed

  hipMemsetAsync(stats, 0, 520 * sizeof(float), stream);
  hipMemsetAsync(rowptr, 0, (Nn + 1) * sizeof(int), stream);

  const int eGrid = (Ne + 255) / 256;
  const int nGrid = (Nn + 255) / 256;
  const int gatherGrid = (Nn * 64 + 255) / 256;
  const int gemmGrid = (Nn + 63) / 64;

  // ---- CSR build (once; reused by all 3 layers) ----
  edge_hist<<<eGrid, 256, 0, stream>>>(dst, rowptr);
  scan_rowptr<<<1, 1024, 0, stream>>>(rowptr);
  copy_cur<<<nGrid, 256, 0, stream>>>(rowptr, cur);
  edge_fill<<<eGrid, 256, 0, stream>>>(src, dst, cur, cols);

  // ---- layer 1 ----
  gather_bn<false><<<gatherGrid, 256, 0, stream>>>(x, rowptr, cols, nullptr, nullptr,
                                                   nullptr, bufA);
  gemm128<false><<<gemmGrid, 256, 0, stream>>>(bufA, W1a, b1a, bufB, nullptr, Nn);
  gemm128<true><<<gemmGrid, 256, 0, stream>>>(bufB, W1b, b1b, bufA, st1, Nn);

  // ---- layer 2 (BN1 folded into gather) ----
  gather_bn<true><<<gatherGrid, 256, 0, stream>>>(bufA, rowptr, cols, st1, g1, be1, bufB);
  gemm128<false><<<gemmGrid, 256, 0, stream>>>(bufB, W2a, b2a, bufA, nullptr, Nn);
  gemm128<true><<<gemmGrid, 256, 0, stream>>>(bufA, W2b, b2b, bufB, st2, Nn);

  // ---- layer 3 (BN2 folded into gather; output dim 2) ----
  gather_bn<true><<<gatherGrid, 256, 0, stream>>>(bufB, rowptr, cols, st2, g2, be2, bufA);
  gemm128<false><<<gemmGrid, 256, 0, stream>>>(bufA, W5a, b5a, bufB, nullptr, Nn);
  gemm_out2<<<nGrid, 256, 0, stream>>>(bufB, W5b, b5b, o2buf, st3, Nn);
  bn_apply2<<<(Nn * 2 + 255) / 256, 256, 0, stream>>>(o2buf, st3, g5, be5,
                                                      (float*)d_out, Nn);
}

// Round 4
// 342.762 us; speedup vs baseline: 10.7134x; 1.8549x over previous
//
#include <hip/hip_runtime.h>

// GIN 3-layer forward on MI355X — round 4: bf16 h-path + MFMA fused MLPs.

constexpr int Nn = 50000;
constexpr int Ne = 600000;

typedef __attribute__((ext_vector_type(8))) short short8;
typedef __attribute__((ext_vector_type(4))) float f32x4;

// ---------------- bf16 helpers -------------------------------------------
__device__ inline float bflo(uint u) { return __uint_as_float(u << 16); }
__device__ inline float bfhi(uint u) { return __uint_as_float(u & 0xffff0000u); }
__device__ inline ushort f2b(float f) {
  uint x = __float_as_uint(f);
  return (ushort)((x + 0x7fffu + ((x >> 16) & 1u)) >> 16);  // RNE, finite vals
}
__device__ inline uint pack2(float a, float b) {
  return (uint)f2b(a) | ((uint)f2b(b) << 16);
}

// ---------------- x f32 -> bf16 ------------------------------------------
__global__ __launch_bounds__(256) void cvt_bf16(const float4* __restrict__ in,
                                                uint2* __restrict__ out, int n4) {
  int i = blockIdx.x * 256 + threadIdx.x;
  if (i < n4) {
    float4 v = in[i];
    out[i] = make_uint2(pack2(v.x, v.y), pack2(v.z, v.w));
  }
}

// ---------------- pack 5 weight matrices into MFMA A-operand frag order ---
// Aop[i][k] = W[k][col0+i];  lane l holds Aop[l&15][8*(l>>4)+j], j=0..7
// pw[mat*16384 + ((nt*4+kt)*64 + l)*8 + j] = bf16(W[kt*32+8*(l>>4)+j][nt*16+(l&15)])
__global__ __launch_bounds__(256) void pack_w(const float* __restrict__ Wa,
                                              const float* __restrict__ Wb,
                                              const float* __restrict__ Wc,
                                              const float* __restrict__ Wd,
                                              const float* __restrict__ We,
                                              ushort* __restrict__ pw) {
  int t = blockIdx.x * 256 + threadIdx.x;
  if (t >= 5 * 2048) return;
  int mat = t >> 11;
  int r = t & 2047;
  int lane = r & 63;
  int ktnt = r >> 6;
  int kt = ktnt & 3, nt = ktnt >> 2;
  const float* W = mat == 0 ? Wa : mat == 1 ? Wb : mat == 2 ? Wc : mat == 3 ? Wd : We;
  int c = nt * 16 + (lane & 15);
  int k0 = kt * 32 + 8 * (lane >> 4);
  ushort tmp[8];
#pragma unroll
  for (int j = 0; j < 8; j++) tmp[j] = f2b(W[(size_t)(k0 + j) * 128 + c]);
  *(uint4*)&pw[(size_t)mat * 16384 + r * 8] = *(uint4*)tmp;
}

// ---------------- CSR build ----------------------------------------------
__global__ __launch_bounds__(256) void edge_hist(const int* __restrict__ dst,
                                                 int* __restrict__ rp) {
  int e = blockIdx.x * 256 + threadIdx.x;
  if (e < Ne) atomicAdd(&rp[dst[e] + 1], 1);
}

__global__ __launch_bounds__(1024) void scan_rowptr(int* __restrict__ rp) {
  __shared__ int wsum[16];
  __shared__ int wpre[16];
  __shared__ int carry;
  if (threadIdx.x == 0) carry = 0;
  __syncthreads();
  int lane = threadIdx.x & 63;
  int wv = threadIdx.x >> 6;
  for (int base = 0; base < Nn + 1; base += 1024) {
    int i = base + threadIdx.x;
    int v = (i < Nn + 1) ? rp[i] : 0;
#pragma unroll
    for (int off = 1; off < 64; off <<= 1) {
      int t = __shfl_up(v, off);
      if (lane >= off) v += t;
    }
    if (lane == 63) wsum[wv] = v;
    __syncthreads();
    if (threadIdx.x == 0) {
      int acc = carry;
#pragma unroll
      for (int w = 0; w < 16; w++) {
        wpre[w] = acc;
        acc += wsum[w];
      }
      carry = acc;
    }
    __syncthreads();
    if (i < Nn + 1) rp[i] = v + wpre[wv];
  }
}

__global__ __launch_bounds__(256) void copy_cur(const int* __restrict__ rp,
                                                int* __restrict__ cur) {
  int i = blockIdx.x * 256 + threadIdx.x;
  if (i < Nn) cur[i] = rp[i];
}

__global__ __launch_bounds__(256) void edge_fill(const int* __restrict__ src,
                                                 const int* __restrict__ dst,
                                                 int* __restrict__ cur,
                                                 int* __restrict__ cols) {
  int e = blockIdx.x * 256 + threadIdx.x;
  if (e < Ne) {
    int p = atomicAdd(&cur[dst[e]], 1);
    cols[p] = src[e];
  }
}

// ---------------- gather (bf16 in/out), optional folded BN affine ---------
template <bool FOLD>
__global__ __launch_bounds__(256) void gather_bn(const uint* __restrict__ X,
                                                 const int* __restrict__ rp,
                                                 const int* __restrict__ cols,
                                                 const float* __restrict__ sums,
                                                 const float* __restrict__ gamma,
                                                 const float* __restrict__ beta,
                                                 uint* __restrict__ H) {
  int wid = (blockIdx.x * 256 + threadIdx.x) >> 6;
  if (wid >= Nn) return;
  int lane = threadIdx.x & 63;
  int f0 = lane * 2;
  float A0 = 1.f, A1 = 1.f, B0 = 0.f, B1 = 0.f;
  if (FOLD) {
    float m0 = sums[f0] * (1.f / Nn), m1 = sums[f0 + 1] * (1.f / Nn);
    float v0 = sums[128 + f0] * (1.f / Nn) - m0 * m0;
    float v1 = sums[128 + f0 + 1] * (1.f / Nn) - m1 * m1;
    A0 = rsqrtf(v0 + 1e-5f) * gamma[f0];
    A1 = rsqrtf(v1 + 1e-5f) * gamma[f0 + 1];
    B0 = beta[f0] - m0 * A0;
    B1 = beta[f0 + 1] - m1 * A1;
  }
  int p0 = rp[wid], p1 = rp[wid + 1];
  uint su = X[(size_t)wid * 64 + lane];
  float ax = bflo(su), ay = bfhi(su);
  int p = p0;
  for (; p + 2 <= p1; p += 2) {
    int s0 = cols[p], s1 = cols[p + 1];
    uint u0 = X[(size_t)s0 * 64 + lane];
    uint u1 = X[(size_t)s1 * 64 + lane];
    ax += bflo(u0) + bflo(u1);
    ay += bfhi(u0) + bfhi(u1);
  }
  if (p < p1) {
    uint u0 = X[(size_t)cols[p] * 64 + lane];
    ax += bflo(u0);
    ay += bfhi(u0);
  }
  float cnt = (float)(p1 - p0 + 1);
  float ox = FOLD ? A0 * ax + cnt * B0 : ax;
  float oy = FOLD ? A1 * ay + cnt * B1 : ay;
  H[(size_t)wid * 64 + lane] = pack2(ox, oy);
}

// ---------------- fused MLP: C = relu(relu(A@Wa+ba)@Wb+bb), + stats -------
// 64 rows/block, 16 rows/wave. Swapped MFMA: D = Wfrag x Arow -> lane owns
// row (l&15), cols nt*16 + (l>>4)*4 + r. Intermediate T bounced via LDS.
__global__ __launch_bounds__(256) void gin_mlp(const ushort* __restrict__ A,
                                               const short8* __restrict__ pWa,
                                               const float* __restrict__ ba,
                                               const short8* __restrict__ pWb,
                                               const float* __restrict__ bb,
                                               ushort* __restrict__ C,
                                               float* __restrict__ stats) {
  __shared__ ushort T[64][136];  // 272B row stride: 2-way-free LDS banking
  __shared__ float sS[128], sQ[128];
  int tid = threadIdx.x;
  if (tid < 128) {
    sS[tid] = 0.f;
    sQ[tid] = 0.f;
  }
  __syncthreads();
  int wv = tid >> 6, l = tid & 63, lr = l & 15, lg = l >> 4;
  int rowb = wv * 16 + lr;
  int row = blockIdx.x * 64 + rowb;
  bool ok = row < Nn;

  // ---- GEMM1 ----
  f32x4 acc[8];
#pragma unroll
  for (int nt = 0; nt < 8; nt++) {
    float4 bv = *(const float4*)&ba[nt * 16 + lg * 4];
    acc[nt][0] = bv.x; acc[nt][1] = bv.y; acc[nt][2] = bv.z; acc[nt][3] = bv.w;
  }
#pragma unroll
  for (int kt = 0; kt < 4; kt++) {
    short8 bfr = short8{};
    if (ok) bfr = *(const short8*)(A + (size_t)row * 128 + kt * 32 + lg * 8);
#pragma unroll
    for (int nt = 0; nt < 8; nt++)
      acc[nt] = __builtin_amdgcn_mfma_f32_16x16x32_bf16(pWa[(nt * 4 + kt) * 64 + l],
                                                        bfr, acc[nt], 0, 0, 0);
  }
#pragma unroll
  for (int nt = 0; nt < 8; nt++) {
    float v0 = fmaxf(acc[nt][0], 0.f), v1 = fmaxf(acc[nt][1], 0.f);
    float v2 = fmaxf(acc[nt][2], 0.f), v3 = fmaxf(acc[nt][3], 0.f);
    *(uint2*)&T[rowb][nt * 16 + lg * 4] = make_uint2(pack2(v0, v1), pack2(v2, v3));
  }
  __syncthreads();

  // ---- GEMM2 ----
  f32x4 acc2[8];
#pragma unroll
  for (int nt = 0; nt < 8; nt++) {
    float4 bv = *(const float4*)&bb[nt * 16 + lg * 4];
    acc2[nt][0] = bv.x; acc2[nt][1] = bv.y; acc2[nt][2] = bv.z; acc2[nt][3] = bv.w;
  }
#pragma unroll
  for (int kt = 0; kt < 4; kt++) {
    short8 tf = *(const short8*)&T[rowb][kt * 32 + lg * 8];
#pragma unroll
    for (int nt = 0; nt < 8; nt++)
      acc2[nt] = __builtin_amdgcn_mfma_f32_16x16x32_bf16(pWb[(nt * 4 + kt) * 64 + l],
                                                         tf, acc2[nt], 0, 0, 0);
  }

  // ---- epilogue: relu, store bf16, fused per-feature stats ----
#pragma unroll
  for (int nt = 0; nt < 8; nt++) {
    float v[4];
#pragma unroll
    for (int r = 0; r < 4; r++) v[r] = fmaxf(acc2[nt][r], 0.f);
    if (ok)
      *(uint2*)&C[(size_t)row * 128 + nt * 16 + lg * 4] =
          make_uint2(pack2(v[0], v[1]), pack2(v[2], v[3]));
#pragma unroll
    for (int r = 0; r < 4; r++) {
      float s_ = ok ? v[r] : 0.f;
      float q_ = s_ * s_;
      s_ += __shfl_xor(s_, 1);  q_ += __shfl_xor(q_, 1);
      s_ += __shfl_xor(s_, 2);  q_ += __shfl_xor(q_, 2);
      s_ += __shfl_xor(s_, 4);  q_ += __shfl_xor(q_, 4);
      s_ += __shfl_xor(s_, 8);  q_ += __shfl_xor(q_, 8);
      if (lr == 0) {
        atomicAdd(&sS[nt * 16 + lg * 4 + r], s_);
        atomicAdd(&sQ[nt * 16 + lg * 4 + r], q_);
      }
    }
  }
  __syncthreads();
  if (tid < 128) {
    atomicAdd(&stats[tid], sS[tid]);
    atomicAdd(&stats[128 + tid], sQ[tid]);
  }
}

// ---------------- layer-3 fused MLP: O = relu(relu(A@W5a+b5a)@W5b+b5b) ----
__global__ __launch_bounds__(256) void gin_mlp_out(const ushort* __restrict__ A,
                                                   const short8* __restrict__ pWa,
                                                   const float* __restrict__ ba,
                                                   const float* __restrict__ W5b,
                                                   const float* __restrict__ b5b,
                                                   float* __restrict__ O) {
  __shared__ ushort T[64][136];
  __shared__ float Wc[256];
  int tid = threadIdx.x;
  Wc[tid] = W5b[tid];
  __syncthreads();
  int wv = tid >> 6, l = tid & 63, lr = l & 15, lg = l >> 4;
  int rowb = wv * 16 + lr;
  int row = blockIdx.x * 64 + rowb;
  bool ok = row < Nn;

  f32x4 acc[8];
#pragma unroll
  for (int nt = 0; nt < 8; nt++) {
    float4 bv = *(const float4*)&ba[nt * 16 + lg * 4];
    acc[nt][0] = bv.x; acc[nt][1] = bv.y; acc[nt][2] = bv.z; acc[nt][3] = bv.w;
  }
#pragma unroll
  for (int kt = 0; kt < 4; kt++) {
    short8 bfr = short8{};
    if (ok) bfr = *(const short8*)(A + (size_t)row * 128 + kt * 32 + lg * 8);
#pragma unroll
    for (int nt = 0; nt < 8; nt++)
      acc[nt] = __builtin_amdgcn_mfma_f32_16x16x32_bf16(pWa[(nt * 4 + kt) * 64 + l],
                                                        bfr, acc[nt], 0, 0, 0);
  }
#pragma unroll
  for (int nt = 0; nt < 8; nt++) {
    float v0 = fmaxf(acc[nt][0], 0.f), v1 = fmaxf(acc[nt][1], 0.f);
    float v2 = fmaxf(acc[nt][2], 0.f), v3 = fmaxf(acc[nt][3], 0.f);
    *(uint2*)&T[rowb][nt * 16 + lg * 4] = make_uint2(pack2(v0, v1), pack2(v2, v3));
  }
  __syncthreads();

  // out2: lane handles row (wv*16 + lr), k-slice lg*32
  float a0 = 0.f, a1 = 0.f;
  int ks = lg * 32;
#pragma unroll
  for (int q = 0; q < 4; q++) {
    uint4 u = *(const uint4*)&T[rowb][ks + q * 8];
    uint uu[4] = {u.x, u.y, u.z, u.w};
#pragma unroll
    for (int h = 0; h < 4; h++) {
      int k = ks + q * 8 + h * 2;
      float e0 = bflo(uu[h]), e1 = bfhi(uu[h]);
      a0 = fmaf(e0, Wc[k * 2 + 0], a0);
      a1 = fmaf(e0, Wc[k * 2 + 1], a1);
      a0 = fmaf(e1, Wc[k * 2 + 2], a0);
      a1 = fmaf(e1, Wc[k * 2 + 3], a1);
    }
  }
  a0 += __shfl_xor(a0, 16);
  a0 += __shfl_xor(a0, 32);
  a1 += __shfl_xor(a1, 16);
  a1 += __shfl_xor(a1, 32);
  if (l < 16 && ok) {
    float o0 = fmaxf(a0 + b5b[0], 0.f);
    float o1 = fmaxf(a1 + b5b[1], 0.f);
    *(float2*)&O[(size_t)row * 2] = make_float2(o0, o1);
  }
}

// ---------------- stats over 2-feature output -----------------------------
__global__ __launch_bounds__(256) void bn_stats2(const float* __restrict__ O,
                                                 float* __restrict__ st) {
  int idx = blockIdx.x * 256 + threadIdx.x;
  float s0 = 0.f, q0 = 0.f, s1 = 0.f, q1 = 0.f;
  for (int r = idx; r < Nn; r += 64 * 256) {
    float2 v = *(const float2*)&O[(size_t)r * 2];
    s0 += v.x; q0 += v.x * v.x;
    s1 += v.y; q1 += v.y * v.y;
  }
#pragma unroll
  for (int off = 1; off < 64; off <<= 1) {
    s0 += __shfl_xor(s0, off);
    q0 += __shfl_xor(q0, off);
    s1 += __shfl_xor(s1, off);
    q1 += __shfl_xor(q1, off);
  }
  __shared__ float red[4][4];
  int wv = threadIdx.x >> 6;
  if ((threadIdx.x & 63) == 0) {
    red[wv][0] = s0; red[wv][1] = s1; red[wv][2] = q0; red[wv][3] = q1;
  }
  __syncthreads();
  if (threadIdx.x < 4) {
    float t = red[0][threadIdx.x] + red[1][threadIdx.x] + red[2][threadIdx.x] +
              red[3][threadIdx.x];
    atomicAdd(&st[threadIdx.x], t);
  }
}

__global__ __launch_bounds__(256) void bn_apply2(const float* __restrict__ H,
                                                 const float* __restrict__ sums,
                                                 const float* __restrict__ gamma,
                                                 const float* __restrict__ beta,
                                                 float* __restrict__ Out, int nRows) {
  int idx = blockIdx.x * 256 + threadIdx.x;
  if (idx >= nRows * 2) return;
  int f = idx & 1;
  float mean = sums[f] * (1.0f / Nn);
  float var = sums[2 + f] * (1.0f / Nn) - mean * mean;
  float inv = rsqrtf(var + 1e-5f);
  Out[idx] = (H[idx] - mean) * inv * gamma[f] + beta[f];
}

extern "C" void kernel_launch(void* const* d_in, const int* in_sizes, int n_in,
                              void* d_out, int out_size, void* d_ws, size_t ws_size,
                              hipStream_t stream) {
  const float* x = (const float*)d_in[0];
  const int* src = (const int*)d_in[1];
  const int* dst = src + Ne;
  const float* W1a = (const float*)d_in[2];
  const float* b1a = (const float*)d_in[3];
  const float* W1b = (const float*)d_in[4];
  const float* b1b = (const float*)d_in[5];
  const float* g1 = (const float*)d_in[6];
  const float* be1 = (const float*)d_in[7];
  const float* W2a = (const float*)d_in[8];
  const float* b2a = (const float*)d_in[9];
  const float* W2b = (const float*)d_in[10];
  const float* b2b = (const float*)d_in[11];
  const float* g2 = (const float*)d_in[12];
  const float* be2 = (const float*)d_in[13];
  const float* W5a = (const float*)d_in[14];
  const float* b5a = (const float*)d_in[15];
  const float* W5b = (const float*)d_in[16];
  const float* b5b = (const float*)d_in[17];
  const float* g5 = (const float*)d_in[18];
  const float* be5 = (const float*)d_in[19];

  // ---- workspace carve (all 256B-aligned) ----
  char* base = (char*)d_ws;
  size_t off = 0;
  auto carve = [&](size_t bytes) {
    char* p = base + off;
    off += (bytes + 255) & ~(size_t)255;
    return p;
  };
  float* stats = (float*)carve(520 * 4);       // st1[256] st2[256] st3[4+]
  float* o2buf = (float*)carve((size_t)Nn * 2 * 4);
  int* rowptr = (int*)carve((size_t)(Nn + 1) * 4);
  int* cur = (int*)carve((size_t)Nn * 4);
  int* cols = (int*)carve((size_t)Ne * 4);
  ushort* xb = (ushort*)carve((size_t)Nn * 128 * 2);
  ushort* bufA = (ushort*)carve((size_t)Nn * 128 * 2);
  ushort* bufB = (ushort*)carve((size_t)Nn * 128 * 2);
  ushort* pw = (ushort*)carve((size_t)5 * 16384 * 2);
  float* st1 = stats, *st2 = stats + 256, *st3 = stats + 512;

  hipMemsetAsync(stats, 0, 520 * sizeof(float), stream);
  hipMemsetAsync(rowptr, 0, (Nn + 1) * sizeof(int), stream);

  const int eGrid = (Ne + 255) / 256;
  const int nGrid = (Nn + 255) / 256;
  const int gatherGrid = (Nn * 64 + 255) / 256;
  const int mlpGrid = (Nn + 63) / 64;

  // ---- prep: convert x, pack weights, CSR ----
  cvt_bf16<<<(Nn * 32 + 255) / 256, 256, 0, stream>>>((const float4*)x, (uint2*)xb,
                                                      Nn * 32);
  pack_w<<<(5 * 2048 + 255) / 256, 256, 0, stream>>>(W1a, W1b, W2a, W2b, W5a, pw);
  edge_hist<<<eGrid, 256, 0, stream>>>(dst, rowptr);
  scan_rowptr<<<1, 1024, 0, stream>>>(rowptr);
  copy_cur<<<nGrid, 256, 0, stream>>>(rowptr, cur);
  edge_fill<<<eGrid, 256, 0, stream>>>(src, dst, cur, cols);

  const short8* pW1a = (const short8*)pw;
  const short8* pW1b = (const short8*)(pw + 16384);
  const short8* pW2a = (const short8*)(pw + 32768);
  const short8* pW2b = (const short8*)(pw + 49152);
  const short8* pW5a = (const short8*)(pw + 65536);

  // ---- layer 1 ----
  gather_bn<false><<<gatherGrid, 256, 0, stream>>>((const uint*)xb, rowptr, cols,
                                                   nullptr, nullptr, nullptr,
                                                   (uint*)bufA);
  gin_mlp<<<mlpGrid, 256, 0, stream>>>(bufA, pW1a, b1a, pW1b, b1b, bufB, st1);

  // ---- layer 2 ----
  gather_bn<true><<<gatherGrid, 256, 0, stream>>>((const uint*)bufB, rowptr, cols, st1,
                                                  g1, be1, (uint*)bufA);
  gin_mlp<<<mlpGrid, 256, 0, stream>>>(bufA, pW2a, b2a, pW2b, b2b, bufB, st2);

  // ---- layer 3 ----
  gather_bn<true><<<gatherGrid, 256, 0, stream>>>((const uint*)bufB, rowptr, cols, st2,
                                                  g2, be2, (uint*)bufA);
  gin_mlp_out<<<mlpGrid, 256, 0, stream>>>(bufA, pW5a, b5a, W5b, b5b, o2buf);
  bn_stats2<<<64, 256, 0, stream>>>(o2buf, st3);
  bn_apply2<<<(Nn * 2 + 255) / 256, 256, 0, stream>>>(o2buf, st3, g5, be5,
                                                      (float*)d_out, Nn);
}

// Round 5
// 303.484 us; speedup vs baseline: 12.0999x; 1.1294x over previous
//
#include <hip/hip_runtime.h>

// GIN 3-layer forward on MI355X — round 5: register-resident MFMA weights
// (launch_bounds(256,2)), multi-block rowptr scan.

constexpr int Nn = 50000;
constexpr int Ne = 600000;

typedef __attribute__((ext_vector_type(8))) short short8;
typedef __attribute__((ext_vector_type(4))) float f32x4;

// ---------------- bf16 helpers -------------------------------------------
__device__ inline float bflo(uint u) { return __uint_as_float(u << 16); }
__device__ inline float bfhi(uint u) { return __uint_as_float(u & 0xffff0000u); }
__device__ inline ushort f2b(float f) {
  uint x = __float_as_uint(f);
  return (ushort)((x + 0x7fffu + ((x >> 16) & 1u)) >> 16);  // RNE, finite vals
}
__device__ inline uint pack2(float a, float b) {
  return (uint)f2b(a) | ((uint)f2b(b) << 16);
}

// ---------------- x f32 -> bf16 ------------------------------------------
__global__ __launch_bounds__(256) void cvt_bf16(const float4* __restrict__ in,
                                                uint2* __restrict__ out, int n4) {
  int i = blockIdx.x * 256 + threadIdx.x;
  if (i < n4) {
    float4 v = in[i];
    out[i] = make_uint2(pack2(v.x, v.y), pack2(v.z, v.w));
  }
}

// ---------------- pack 5 weight matrices into MFMA A-operand frag order ---
__global__ __launch_bounds__(256) void pack_w(const float* __restrict__ Wa,
                                              const float* __restrict__ Wb,
                                              const float* __restrict__ Wc,
                                              const float* __restrict__ Wd,
                                              const float* __restrict__ We,
                                              ushort* __restrict__ pw) {
  int t = blockIdx.x * 256 + threadIdx.x;
  if (t >= 5 * 2048) return;
  int mat = t >> 11;
  int r = t & 2047;
  int lane = r & 63;
  int ktnt = r >> 6;
  int kt = ktnt & 3, nt = ktnt >> 2;
  const float* W = mat == 0 ? Wa : mat == 1 ? Wb : mat == 2 ? Wc : mat == 3 ? Wd : We;
  int c = nt * 16 + (lane & 15);
  int k0 = kt * 32 + 8 * (lane >> 4);
  ushort tmp[8];
#pragma unroll
  for (int j = 0; j < 8; j++) tmp[j] = f2b(W[(size_t)(k0 + j) * 128 + c]);
  *(uint4*)&pw[(size_t)mat * 16384 + r * 8] = *(uint4*)tmp;
}

// ---------------- CSR build ----------------------------------------------
__global__ __launch_bounds__(256) void edge_hist(const int* __restrict__ dst,
                                                 int* __restrict__ rp) {
  int e = blockIdx.x * 256 + threadIdx.x;
  if (e < Ne) atomicAdd(&rp[dst[e] + 1], 1);
}

constexpr int SCAN_N = Nn + 1;
constexpr int SCAN_G = (SCAN_N + 1023) / 1024;  // 49

// phase 1: per-block inclusive scan in-place, block total -> bsum[b]
__global__ __launch_bounds__(1024) void scan_p1(int* __restrict__ rp,
                                                int* __restrict__ bsum) {
  __shared__ int wsum[16];
  __shared__ int wpre[16];
  int i = blockIdx.x * 1024 + threadIdx.x;
  int lane = threadIdx.x & 63, wv = threadIdx.x >> 6;
  int v = (i < SCAN_N) ? rp[i] : 0;
#pragma unroll
  for (int off = 1; off < 64; off <<= 1) {
    int t = __shfl_up(v, off);
    if (lane >= off) v += t;
  }
  if (lane == 63) wsum[wv] = v;
  __syncthreads();
  if (threadIdx.x == 0) {
    int acc = 0;
#pragma unroll
    for (int w = 0; w < 16; w++) {
      wpre[w] = acc;
      acc += wsum[w];
    }
    bsum[blockIdx.x] = acc;
  }
  __syncthreads();
  if (i < SCAN_N) rp[i] = v + wpre[wv];
}

// phase 2: exclusive scan of bsum[SCAN_G] (tiny, 1 thread)
__global__ void scan_p2(int* __restrict__ bsum) {
  if (threadIdx.x == 0 && blockIdx.x == 0) {
    int acc = 0;
    for (int b = 0; b < SCAN_G; b++) {
      int t = bsum[b];
      bsum[b] = acc;
      acc += t;
    }
  }
}

// phase 3: add block offsets
__global__ __launch_bounds__(1024) void scan_p3(int* __restrict__ rp,
                                                const int* __restrict__ bsum) {
  int i = blockIdx.x * 1024 + threadIdx.x;
  if (i < SCAN_N) rp[i] += bsum[blockIdx.x];
}

__global__ __launch_bounds__(256) void copy_cur(const int* __restrict__ rp,
                                                int* __restrict__ cur) {
  int i = blockIdx.x * 256 + threadIdx.x;
  if (i < Nn) cur[i] = rp[i];
}

__global__ __launch_bounds__(256) void edge_fill(const int* __restrict__ src,
                                                 const int* __restrict__ dst,
                                                 int* __restrict__ cur,
                                                 int* __restrict__ cols) {
  int e = blockIdx.x * 256 + threadIdx.x;
  if (e < Ne) {
    int p = atomicAdd(&cur[dst[e]], 1);
    cols[p] = src[e];
  }
}

// ---------------- gather (bf16 in/out), optional folded BN affine ---------
template <bool FOLD>
__global__ __launch_bounds__(256) void gather_bn(const uint* __restrict__ X,
                                                 const int* __restrict__ rp,
                                                 const int* __restrict__ cols,
                                                 const float* __restrict__ sums,
                                                 const float* __restrict__ gamma,
                                                 const float* __restrict__ beta,
                                                 uint* __restrict__ H) {
  int wid = (blockIdx.x * 256 + threadIdx.x) >> 6;
  if (wid >= Nn) return;
  int lane = threadIdx.x & 63;
  int f0 = lane * 2;
  float A0 = 1.f, A1 = 1.f, B0 = 0.f, B1 = 0.f;
  if (FOLD) {
    float m0 = sums[f0] * (1.f / Nn), m1 = sums[f0 + 1] * (1.f / Nn);
    float v0 = sums[128 + f0] * (1.f / Nn) - m0 * m0;
    float v1 = sums[128 + f0 + 1] * (1.f / Nn) - m1 * m1;
    A0 = rsqrtf(v0 + 1e-5f) * gamma[f0];
    A1 = rsqrtf(v1 + 1e-5f) * gamma[f0 + 1];
    B0 = beta[f0] - m0 * A0;
    B1 = beta[f0 + 1] - m1 * A1;
  }
  int p0 = rp[wid], p1 = rp[wid + 1];
  uint su = X[(size_t)wid * 64 + lane];
  float ax = bflo(su), ay = bfhi(su);
  int p = p0;
  for (; p + 2 <= p1; p += 2) {
    int s0 = cols[p], s1 = cols[p + 1];
    uint u0 = X[(size_t)s0 * 64 + lane];
    uint u1 = X[(size_t)s1 * 64 + lane];
    ax += bflo(u0) + bflo(u1);
    ay += bfhi(u0) + bfhi(u1);
  }
  if (p < p1) {
    uint u0 = X[(size_t)cols[p] * 64 + lane];
    ax += bflo(u0);
    ay += bfhi(u0);
  }
  float cnt = (float)(p1 - p0 + 1);
  float ox = FOLD ? A0 * ax + cnt * B0 : ax;
  float oy = FOLD ? A1 * ay + cnt * B1 : ay;
  H[(size_t)wid * 64 + lane] = pack2(ox, oy);
}

// ---------------- fused MLP: C = relu(relu(A@Wa+ba)@Wb+bb), + stats -------
// Weights preloaded to registers (static indices, fully unrolled).
__global__ __launch_bounds__(256, 2) void gin_mlp(const ushort* __restrict__ A,
                                                  const short8* __restrict__ pWa,
                                                  const float* __restrict__ ba,
                                                  const short8* __restrict__ pWb,
                                                  const float* __restrict__ bb,
                                                  ushort* __restrict__ C,
                                                  float* __restrict__ stats) {
  __shared__ ushort T[64][136];
  __shared__ float sS[128], sQ[128];
  int tid = threadIdx.x;
  if (tid < 128) {
    sS[tid] = 0.f;
    sQ[tid] = 0.f;
  }
  int wv = tid >> 6, l = tid & 63, lr = l & 15, lg = l >> 4;
  int rowb = wv * 16 + lr;
  int row = blockIdx.x * 64 + rowb;
  bool ok = row < Nn;

  // ---- preload GEMM1 weights + A-row fragments (all loads in flight) ----
  short8 w[8][4];
#pragma unroll
  for (int nt = 0; nt < 8; nt++)
#pragma unroll
    for (int kt = 0; kt < 4; kt++) w[nt][kt] = pWa[(nt * 4 + kt) * 64 + l];
  short8 afr[4];
#pragma unroll
  for (int kt = 0; kt < 4; kt++) {
    afr[kt] = short8{};
    if (ok) afr[kt] = *(const short8*)(A + (size_t)row * 128 + kt * 32 + lg * 8);
  }
  f32x4 acc[8];
#pragma unroll
  for (int nt = 0; nt < 8; nt++) {
    float4 bv = *(const float4*)&ba[nt * 16 + lg * 4];
    acc[nt][0] = bv.x; acc[nt][1] = bv.y; acc[nt][2] = bv.z; acc[nt][3] = bv.w;
  }
  __syncthreads();  // sS/sQ init done; also spaces the load wave
#pragma unroll
  for (int kt = 0; kt < 4; kt++)
#pragma unroll
    for (int nt = 0; nt < 8; nt++)
      acc[nt] = __builtin_amdgcn_mfma_f32_16x16x32_bf16(w[nt][kt], afr[kt], acc[nt],
                                                        0, 0, 0);
#pragma unroll
  for (int nt = 0; nt < 8; nt++) {
    float v0 = fmaxf(acc[nt][0], 0.f), v1 = fmaxf(acc[nt][1], 0.f);
    float v2 = fmaxf(acc[nt][2], 0.f), v3 = fmaxf(acc[nt][3], 0.f);
    *(uint2*)&T[rowb][nt * 16 + lg * 4] = make_uint2(pack2(v0, v1), pack2(v2, v3));
  }
  __syncthreads();

  // ---- GEMM2: preload W2 into same register block ----
  short8 w2[8][4];
#pragma unroll
  for (int nt = 0; nt < 8; nt++)
#pragma unroll
    for (int kt = 0; kt < 4; kt++) w2[nt][kt] = pWb[(nt * 4 + kt) * 64 + l];
  short8 tfr[4];
#pragma unroll
  for (int kt = 0; kt < 4; kt++) tfr[kt] = *(const short8*)&T[rowb][kt * 32 + lg * 8];
  f32x4 acc2[8];
#pragma unroll
  for (int nt = 0; nt < 8; nt++) {
    float4 bv = *(const float4*)&bb[nt * 16 + lg * 4];
    acc2[nt][0] = bv.x; acc2[nt][1] = bv.y; acc2[nt][2] = bv.z; acc2[nt][3] = bv.w;
  }
#pragma unroll
  for (int kt = 0; kt < 4; kt++)
#pragma unroll
    for (int nt = 0; nt < 8; nt++)
      acc2[nt] = __builtin_amdgcn_mfma_f32_16x16x32_bf16(w2[nt][kt], tfr[kt], acc2[nt],
                                                         0, 0, 0);

  // ---- epilogue: relu, store bf16, fused per-feature stats ----
#pragma unroll
  for (int nt = 0; nt < 8; nt++) {
    float v[4];
#pragma unroll
    for (int r = 0; r < 4; r++) v[r] = fmaxf(acc2[nt][r], 0.f);
    if (ok)
      *(uint2*)&C[(size_t)row * 128 + nt * 16 + lg * 4] =
          make_uint2(pack2(v[0], v[1]), pack2(v[2], v[3]));
#pragma unroll
    for (int r = 0; r < 4; r++) {
      float s_ = ok ? v[r] : 0.f;
      float q_ = s_ * s_;
      s_ += __shfl_xor(s_, 1);  q_ += __shfl_xor(q_, 1);
      s_ += __shfl_xor(s_, 2);  q_ += __shfl_xor(q_, 2);
      s_ += __shfl_xor(s_, 4);  q_ += __shfl_xor(q_, 4);
      s_ += __shfl_xor(s_, 8);  q_ += __shfl_xor(q_, 8);
      if (lr == 0) {
        atomicAdd(&sS[nt * 16 + lg * 4 + r], s_);
        atomicAdd(&sQ[nt * 16 + lg * 4 + r], q_);
      }
    }
  }
  __syncthreads();
  if (tid < 128) {
    atomicAdd(&stats[tid], sS[tid]);
    atomicAdd(&stats[128 + tid], sQ[tid]);
  }
}

// ---------------- layer-3 fused MLP: O = relu(relu(A@W5a+b5a)@W5b+b5b) ----
__global__ __launch_bounds__(256, 2) void gin_mlp_out(const ushort* __restrict__ A,
                                                      const short8* __restrict__ pWa,
                                                      const float* __restrict__ ba,
                                                      const float* __restrict__ W5b,
                                                      const float* __restrict__ b5b,
                                                      float* __restrict__ O) {
  __shared__ ushort T[64][136];
  __shared__ float Wc[256];
  int tid = threadIdx.x;
  Wc[tid] = W5b[tid];
  int wv = tid >> 6, l = tid & 63, lr = l & 15, lg = l >> 4;
  int rowb = wv * 16 + lr;
  int row = blockIdx.x * 64 + rowb;
  bool ok = row < Nn;

  short8 w[8][4];
#pragma unroll
  for (int nt = 0; nt < 8; nt++)
#pragma unroll
    for (int kt = 0; kt < 4; kt++) w[nt][kt] = pWa[(nt * 4 + kt) * 64 + l];
  short8 afr[4];
#pragma unroll
  for (int kt = 0; kt < 4; kt++) {
    afr[kt] = short8{};
    if (ok) afr[kt] = *(const short8*)(A + (size_t)row * 128 + kt * 32 + lg * 8);
  }
  f32x4 acc[8];
#pragma unroll
  for (int nt = 0; nt < 8; nt++) {
    float4 bv = *(const float4*)&ba[nt * 16 + lg * 4];
    acc[nt][0] = bv.x; acc[nt][1] = bv.y; acc[nt][2] = bv.z; acc[nt][3] = bv.w;
  }
  __syncthreads();
#pragma unroll
  for (int kt = 0; kt < 4; kt++)
#pragma unroll
    for (int nt = 0; nt < 8; nt++)
      acc[nt] = __builtin_amdgcn_mfma_f32_16x16x32_bf16(w[nt][kt], afr[kt], acc[nt],
                                                        0, 0, 0);
#pragma unroll
  for (int nt = 0; nt < 8; nt++) {
    float v0 = fmaxf(acc[nt][0], 0.f), v1 = fmaxf(acc[nt][1], 0.f);
    float v2 = fmaxf(acc[nt][2], 0.f), v3 = fmaxf(acc[nt][3], 0.f);
    *(uint2*)&T[rowb][nt * 16 + lg * 4] = make_uint2(pack2(v0, v1), pack2(v2, v3));
  }
  __syncthreads();

  float a0 = 0.f, a1 = 0.f;
  int ks = lg * 32;
#pragma unroll
  for (int q = 0; q < 4; q++) {
    uint4 u = *(const uint4*)&T[rowb][ks + q * 8];
    uint uu[4] = {u.x, u.y, u.z, u.w};
#pragma unroll
    for (int h = 0; h < 4; h++) {
      int k = ks + q * 8 + h * 2;
      float e0 = bflo(uu[h]), e1 = bfhi(uu[h]);
      a0 = fmaf(e0, Wc[k * 2 + 0], a0);
      a1 = fmaf(e0, Wc[k * 2 + 1], a1);
      a0 = fmaf(e1, Wc[k * 2 + 2], a0);
      a1 = fmaf(e1, Wc[k * 2 + 3], a1);
    }
  }
  a0 += __shfl_xor(a0, 16);
  a0 += __shfl_xor(a0, 32);
  a1 += __shfl_xor(a1, 16);
  a1 += __shfl_xor(a1, 32);
  if (l < 16 && ok) {
    float o0 = fmaxf(a0 + b5b[0], 0.f);
    float o1 = fmaxf(a1 + b5b[1], 0.f);
    *(float2*)&O[(size_t)row * 2] = make_float2(o0, o1);
  }
}

// ---------------- stats over 2-feature output -----------------------------
__global__ __launch_bounds__(256) void bn_stats2(const float* __restrict__ O,
                                                 float* __restrict__ st) {
  int idx = blockIdx.x * 256 + threadIdx.x;
  float s0 = 0.f, q0 = 0.f, s1 = 0.f, q1 = 0.f;
  for (int r = idx; r < Nn; r += 64 * 256) {
    float2 v = *(const float2*)&O[(size_t)r * 2];
    s0 += v.x; q0 += v.x * v.x;
    s1 += v.y; q1 += v.y * v.y;
  }
#pragma unroll
  for (int off = 1; off < 64; off <<= 1) {
    s0 += __shfl_xor(s0, off);
    q0 += __shfl_xor(q0, off);
    s1 += __shfl_xor(s1, off);
    q1 += __shfl_xor(q1, off);
  }
  __shared__ float red[4][4];
  int wv = threadIdx.x >> 6;
  if ((threadIdx.x & 63) == 0) {
    red[wv][0] = s0; red[wv][1] = s1; red[wv][2] = q0; red[wv][3] = q1;
  }
  __syncthreads();
  if (threadIdx.x < 4) {
    float t = red[0][threadIdx.x] + red[1][threadIdx.x] + red[2][threadIdx.x] +
              red[3][threadIdx.x];
    atomicAdd(&st[threadIdx.x], t);
  }
}

__global__ __launch_bounds__(256) void bn_apply2(const float* __restrict__ H,
                                                 const float* __restrict__ sums,
                                                 const float* __restrict__ gamma,
                                                 const float* __restrict__ beta,
                                                 float* __restrict__ Out, int nRows) {
  int idx = blockIdx.x * 256 + threadIdx.x;
  if (idx >= nRows * 2) return;
  int f = idx & 1;
  float mean = sums[f] * (1.0f / Nn);
  float var = sums[2 + f] * (1.0f / Nn) - mean * mean;
  float inv = rsqrtf(var + 1e-5f);
  Out[idx] = (H[idx] - mean) * inv * gamma[f] + beta[f];
}

extern "C" void kernel_launch(void* const* d_in, const int* in_sizes, int n_in,
                              void* d_out, int out_size, void* d_ws, size_t ws_size,
                              hipStream_t stream) {
  const float* x = (const float*)d_in[0];
  const int* src = (const int*)d_in[1];
  const int* dst = src + Ne;
  const float* W1a = (const float*)d_in[2];
  const float* b1a = (const float*)d_in[3];
  const float* W1b = (const float*)d_in[4];
  const float* b1b = (const float*)d_in[5];
  const float* g1 = (const float*)d_in[6];
  const float* be1 = (const float*)d_in[7];
  const float* W2a = (const float*)d_in[8];
  const float* b2a = (const float*)d_in[9];
  const float* W2b = (const float*)d_in[10];
  const float* b2b = (const float*)d_in[11];
  const float* g2 = (const float*)d_in[12];
  const float* be2 = (const float*)d_in[13];
  const float* W5a = (const float*)d_in[14];
  const float* b5a = (const float*)d_in[15];
  const float* W5b = (const float*)d_in[16];
  const float* b5b = (const float*)d_in[17];
  const float* g5 = (const float*)d_in[18];
  const float* be5 = (const float*)d_in[19];

  // ---- workspace carve (all 256B-aligned) ----
  char* base = (char*)d_ws;
  size_t off = 0;
  auto carve = [&](size_t bytes) {
    char* p = base + off;
    off += (bytes + 255) & ~(size_t)255;
    return p;
  };
  float* stats = (float*)carve(520 * 4);
  float* o2buf = (float*)carve((size_t)Nn * 2 * 4);
  int* rowptr = (int*)carve((size_t)(Nn + 1) * 4);
  int* cur = (int*)carve((size_t)Nn * 4);
  int* cols = (int*)carve((size_t)Ne * 4);
  int* bsum = (int*)carve((size_t)SCAN_G * 4);
  ushort* xb = (ushort*)carve((size_t)Nn * 128 * 2);
  ushort* bufA = (ushort*)carve((size_t)Nn * 128 * 2);
  ushort* bufB = (ushort*)carve((size_t)Nn * 128 * 2);
  ushort* pw = (ushort*)carve((size_t)5 * 16384 * 2);
  float* st1 = stats, *st2 = stats + 256, *st3 = stats + 512;

  hipMemsetAsync(stats, 0, 520 * sizeof(float), stream);
  hipMemsetAsync(rowptr, 0, (Nn + 1) * sizeof(int), stream);

  const int eGrid = (Ne + 255) / 256;
  const int nGrid = (Nn + 255) / 256;
  const int gatherGrid = (Nn * 64 + 255) / 256;
  const int mlpGrid = (Nn + 63) / 64;

  // ---- prep: convert x, pack weights, CSR ----
  cvt_bf16<<<(Nn * 32 + 255) / 256, 256, 0, stream>>>((const float4*)x, (uint2*)xb,
                                                      Nn * 32);
  pack_w<<<(5 * 2048 + 255) / 256, 256, 0, stream>>>(W1a, W1b, W2a, W2b, W5a, pw);
  edge_hist<<<eGrid, 256, 0, stream>>>(dst, rowptr);
  scan_p1<<<SCAN_G, 1024, 0, stream>>>(rowptr, bsum);
  scan_p2<<<1, 64, 0, stream>>>(bsum);
  scan_p3<<<SCAN_G, 1024, 0, stream>>>(rowptr, bsum);
  copy_cur<<<nGrid, 256, 0, stream>>>(rowptr, cur);
  edge_fill<<<eGrid, 256, 0, stream>>>(src, dst, cur, cols);

  const short8* pW1a = (const short8*)pw;
  const short8* pW1b = (const short8*)(pw + 16384);
  const short8* pW2a = (const short8*)(pw + 32768);
  const short8* pW2b = (const short8*)(pw + 49152);
  const short8* pW5a = (const short8*)(pw + 65536);

  // ---- layer 1 ----
  gather_bn<false><<<gatherGrid, 256, 0, stream>>>((const uint*)xb, rowptr, cols,
                                                   nullptr, nullptr, nullptr,
                                                   (uint*)bufA);
  gin_mlp<<<mlpGrid, 256, 0, stream>>>(bufA, pW1a, b1a, pW1b, b1b, bufB, st1);

  // ---- layer 2 ----
  gather_bn<true><<<gatherGrid, 256, 0, stream>>>((const uint*)bufB, rowptr, cols, st1,
                                                  g1, be1, (uint*)bufA);
  gin_mlp<<<mlpGrid, 256, 0, stream>>>(bufA, pW2a, b2a, pW2b, b2b, bufB, st2);

  // ---- layer 3 ----
  gather_bn<true><<<gatherGrid, 256, 0, stream>>>((const uint*)bufB, rowptr, cols, st2,
                                                  g2, be2, (uint*)bufA);
  gin_mlp_out<<<mlpGrid, 256, 0, stream>>>(bufA, pW5a, b5a, W5b, b5b, o2buf);
  bn_stats2<<<64, 256, 0, stream>>>(o2buf, st3);
  bn_apply2<<<(Nn * 2 + 255) / 256, 256, 0, stream>>>(o2buf, st3, g5, be5,
                                                      (float*)d_out, Nn);
}